// Round 4
// baseline (103.712 us; speedup 1.0000x reference)
//
#include <hip/hip_runtime.h>
#include <hip/hip_bf16.h>

#define B_ 2
#define S_ 1024
#define E_ 128
#define H_ 4
#define D_ 32
#define BHSD (B_ * H_ * S_ * D_)   // 262144 floats per tensor
#define LOG2E 1.44269504088896f

// ---------------------------------------------------------------------------
// Kernel A: fused QKV projection.
//   q/k/v[e] = sum_c x[row][c] * W[e][c] + b[e], written in (B,H,S,D) layout.
//   Q and K are pre-scaled by log2(e) so the attention hot loop can use a
//   bare exp2 (v_exp_f32) instead of mul+exp.
// grid = (row_tiles=256, mat=3), block = 128 threads (thread = output col e).
// ---------------------------------------------------------------------------
__global__ __launch_bounds__(128) void qkv_kernel(
    const float* __restrict__ x,
    const float* __restrict__ Wq, const float* __restrict__ bq,
    const float* __restrict__ Wk, const float* __restrict__ bk,
    const float* __restrict__ Wv, const float* __restrict__ bv,
    float* __restrict__ ws) {
  const int mat = blockIdx.y;
  const float* W    = (mat == 0) ? Wq : (mat == 1) ? Wk : Wv;
  const float* bias = (mat == 0) ? bq : (mat == 1) ? bk : bv;
  const float scale = (mat == 2) ? 1.0f : LOG2E;
  float* outbase = ws + (size_t)mat * BHSD;

  const int row0 = blockIdx.x * 8;
  const int t = threadIdx.x;

  __shared__ __align__(16) float xs[8 * E_];
  const float4* xg = (const float4*)(x + (size_t)row0 * E_);
  float4* xs4 = (float4*)xs;
  #pragma unroll
  for (int i = 0; i < 2; ++i) xs4[t + i * 128] = xg[t + i * 128];
  __syncthreads();

  const int col = t;                       // output feature e in [0,128)
  const float4* W4 = (const float4*)(W + (size_t)col * E_);

  float acc[8];
  #pragma unroll
  for (int r = 0; r < 8; ++r) acc[r] = 0.f;

  #pragma unroll 4
  for (int c4 = 0; c4 < E_ / 4; ++c4) {
    float4 w = W4[c4];
    #pragma unroll
    for (int r = 0; r < 8; ++r) {
      float4 xv = xs4[r * (E_ / 4) + c4];
      acc[r] += xv.x * w.x + xv.y * w.y + xv.z * w.z + xv.w * w.w;
    }
  }

  const float bcol = bias[col];
  const int h = col >> 5, d = col & 31;
  #pragma unroll
  for (int r = 0; r < 8; ++r) {
    int row = row0 + r;                    // flat row over B*S
    int b = row >> 10, s = row & 1023;
    outbase[(((size_t)(b * H_ + h)) * S_ + s) * D_ + d] = (acc[r] + bcol) * scale;
  }
}

// ---------------------------------------------------------------------------
// Kernel B: ultrametric attention partials, lane-per-Q-row.
//   Each lane holds one full Q row (32 f32) + accumulator o[32]; the wave
//   walks its 32-key sub-chunk with wave-uniform K/V row loads (scalar path,
//   L1/L2-resident). dist >= 0 so p = exp2(-dist_scaled) needs NO online
//   rescaling in fp32.
// grid = 128 row-tiles * 4 key-chunks = 512 blocks, block = 512 (8 waves).
// Wave w covers keys [kc*256 + w*32, +32). 8-wave merge: waves 4-7 write
// a [4][64][33] LDS buffer, waves 0-3 add into it (fits 64 KB static LDS),
// then the block writes ONE raw partial (o,l) per row. kc merge in out_kernel.
// ---------------------------------------------------------------------------
__global__ __launch_bounds__(512) void attn_kernel(
    const float* __restrict__ qg, const float* __restrict__ kg,
    const float* __restrict__ vg,
    float* __restrict__ part_o, float* __restrict__ part_l) {
  const int rt = blockIdx.x >> 2;      // row tile 0..127
  const int kc = blockIdx.x & 3;       // key chunk 0..3
  const int t = threadIdx.x;
  const int w = t >> 6;                // wave 0..7
  const int lane = t & 63;
  const int bh = rt >> 4;              // head index (b*H + h), uniform
  const int srow = (rt & 15) * 64 + lane;   // s of my Q row

  // Q row -> registers
  const float* qrow = qg + ((size_t)bh * S_ + srow) * D_;
  float q[32];
  #pragma unroll
  for (int i = 0; i < 8; ++i) {
    float4 v4 = *(const float4*)(qrow + i * 4);
    q[i * 4 + 0] = v4.x; q[i * 4 + 1] = v4.y;
    q[i * 4 + 2] = v4.z; q[i * 4 + 3] = v4.w;
  }

  float o[32];
  #pragma unroll
  for (int i = 0; i < 32; ++i) o[i] = 0.f;
  float l = 0.f;

  const float* kbase = kg + (size_t)bh * S_ * D_;
  const float* vbase = vg + (size_t)bh * S_ * D_;
  const int j0 = kc * 256 + w * 32;    // this wave's 32-key sub-chunk

  #pragma unroll 2
  for (int j = j0; j < j0 + 32; ++j) {
    const float* kr = kbase + (size_t)j * D_;  // wave-uniform address
    const float* vr = vbase + (size_t)j * D_;

    float kv[32];
    #pragma unroll
    for (int i = 0; i < 8; ++i) {
      float4 v4 = *(const float4*)(kr + i * 4);
      kv[i * 4 + 0] = v4.x; kv[i * 4 + 1] = v4.y;
      kv[i * 4 + 2] = v4.z; kv[i * 4 + 3] = v4.w;
    }

    // Chebyshev distance: 4 independent chains, v_max3-with-abs friendly
    float c0 = 0.f, c1 = 0.f, c2 = 0.f, c3 = 0.f;
    #pragma unroll
    for (int i = 0; i < 4; ++i) {
      c0 = fmaxf(c0, fmaxf(fabsf(q[i*8+0] - kv[i*8+0]), fabsf(q[i*8+1] - kv[i*8+1])));
      c1 = fmaxf(c1, fmaxf(fabsf(q[i*8+2] - kv[i*8+2]), fabsf(q[i*8+3] - kv[i*8+3])));
      c2 = fmaxf(c2, fmaxf(fabsf(q[i*8+4] - kv[i*8+4]), fabsf(q[i*8+5] - kv[i*8+5])));
      c3 = fmaxf(c3, fmaxf(fabsf(q[i*8+6] - kv[i*8+6]), fabsf(q[i*8+7] - kv[i*8+7])));
    }
    const float dist = fmaxf(fmaxf(c0, c1), fmaxf(c2, c3));  // scaled by log2e
    const float p = exp2f(-dist);
    l += p;

    // O += p * V[j]
    #pragma unroll
    for (int i = 0; i < 8; ++i) {
      float4 v4 = *(const float4*)(vr + i * 4);
      o[i * 4 + 0] = fmaf(p, v4.x, o[i * 4 + 0]);
      o[i * 4 + 1] = fmaf(p, v4.y, o[i * 4 + 1]);
      o[i * 4 + 2] = fmaf(p, v4.z, o[i * 4 + 2]);
      o[i * 4 + 3] = fmaf(p, v4.w, o[i * 4 + 3]);
    }
  }

  // ---- 8-wave merge in a 4-buffer LDS (two phases), write raw partial ----
  __shared__ float sm_o[4][64][33];   // 33.8 KB, conflict-free per phase
  __shared__ float sm_l[4][64];
  if (w >= 4) {
    #pragma unroll
    for (int e = 0; e < 32; ++e) sm_o[w - 4][lane][e] = o[e];
    sm_l[w - 4][lane] = l;
  }
  __syncthreads();
  if (w < 4) {
    #pragma unroll
    for (int e = 0; e < 32; ++e) sm_o[w][lane][e] += o[e];
    sm_l[w][lane] += l;
  }
  __syncthreads();

  const int row = t >> 3;             // 0..63
  const int sl = t & 7;               // dim slice: sl*4 .. sl*4+3
  float r4[4];
  #pragma unroll
  for (int e = 0; e < 4; ++e) {
    const int d = sl * 4 + e;
    r4[e] = sm_o[0][row][d] + sm_o[1][row][d] +
            sm_o[2][row][d] + sm_o[3][row][d];
  }
  float* po = part_o + ((size_t)(rt * 4 + kc) * 64 + row) * 32 + sl * 4;
  *(float4*)po = make_float4(r4[0], r4[1], r4[2], r4[3]);
  if (sl == 0) {
    part_l[(size_t)(rt * 4 + kc) * 64 + row] =
        sm_l[0][row] + sm_l[1][row] + sm_l[2][row] + sm_l[3][row];
  }
}

// ---------------------------------------------------------------------------
// Kernel C: merge kc-partials -> att rows in LDS -> out = att @ Wo^T + bo
// grid = 256 blocks (8 flat rows each), block = 128.
// ---------------------------------------------------------------------------
__global__ __launch_bounds__(128) void out_kernel(
    const float* __restrict__ part_o, const float* __restrict__ part_l,
    const float* __restrict__ Wo, const float* __restrict__ bo,
    float* __restrict__ out) {
  const int row0 = blockIdx.x * 8;
  const int t = threadIdx.x;

  __shared__ __align__(16) float xs[8 * E_];

  // build merged attended rows into LDS: xs[i][e], e = h*32 + d
  const int e = t;
  const int h = e >> 5, d = e & 31;
  #pragma unroll
  for (int i = 0; i < 8; ++i) {
    const int r = row0 + i;
    const int b = r >> 10, s = r & 1023;
    const int rt = (b * H_ + h) * 16 + (s >> 6);
    const int lrow = s & 63;
    float acc = 0.f, lsum = 0.f;
    #pragma unroll
    for (int kc = 0; kc < 4; ++kc) {
      const size_t base = (size_t)(rt * 4 + kc) * 64 + lrow;
      acc  += part_o[base * 32 + d];
      lsum += part_l[base];
    }
    xs[i * E_ + e] = acc / lsum;
  }
  __syncthreads();

  const int col = t;
  const float4* W4 = (const float4*)(Wo + (size_t)col * E_);
  const float4* xs4 = (const float4*)xs;

  float acc[8];
  #pragma unroll
  for (int r = 0; r < 8; ++r) acc[r] = 0.f;

  #pragma unroll 4
  for (int c4 = 0; c4 < E_ / 4; ++c4) {
    float4 w = W4[c4];
    #pragma unroll
    for (int r = 0; r < 8; ++r) {
      float4 xv = xs4[r * (E_ / 4) + c4];
      acc[r] += xv.x * w.x + xv.y * w.y + xv.z * w.z + xv.w * w.w;
    }
  }

  const float bcol = bo[col];
  #pragma unroll
  for (int r = 0; r < 8; ++r)
    out[(size_t)(row0 + r) * E_ + col] = acc[r] + bcol;
}

// ---------------------------------------------------------------------------
extern "C" void kernel_launch(void* const* d_in, const int* in_sizes, int n_in,
                              void* d_out, int out_size, void* d_ws, size_t ws_size,
                              hipStream_t stream) {
  const float* x  = (const float*)d_in[0];
  const float* Wq = (const float*)d_in[1];
  const float* bq = (const float*)d_in[2];
  const float* Wk = (const float*)d_in[3];
  const float* bk = (const float*)d_in[4];
  const float* Wv = (const float*)d_in[5];
  const float* bv = (const float*)d_in[6];
  const float* Wo = (const float*)d_in[7];
  const float* bo = (const float*)d_in[8];
  float* ws  = (float*)d_ws;
  float* out = (float*)d_out;

  // ws layout (floats):
  //   [0, BHSD)        q (scaled by log2e)
  //   [BHSD, 2*BHSD)   k (scaled by log2e)
  //   [2*BHSD, 3*BHSD) v
  //   [3*BHSD, +1048576) part_o  : [128 rt][4 kc][64 row][32 d]
  //   then 32768         part_l  : [128 rt][4 kc][64 row]
  float* qd = ws;
  float* kd = ws + (size_t)BHSD;
  float* vd = ws + 2 * (size_t)BHSD;
  float* part_o = ws + 3 * (size_t)BHSD;
  float* part_l = part_o + (size_t)128 * 4 * 64 * 32;

  qkv_kernel<<<dim3((B_ * S_) / 8, 3), 128, 0, stream>>>(x, Wq, bq, Wk, bk, Wv, bv, ws);
  attn_kernel<<<dim3(128 * 4), 512, 0, stream>>>(qd, kd, vd, part_o, part_l);
  out_kernel<<<dim3((B_ * S_) / 8), 128, 0, stream>>>(part_o, part_l, Wo, bo, out);
}

// Round 5
// 74.669 us; speedup vs baseline: 1.3890x; 1.3890x over previous
//
#include <hip/hip_runtime.h>
#include <hip/hip_bf16.h>

#define B_ 2
#define S_ 1024
#define E_ 128
#define H_ 4
#define D_ 32
#define BHSD (B_ * H_ * S_ * D_)   // 262144 floats per tensor
#define LOG2E 1.44269504088896f

// ---------------------------------------------------------------------------
// Kernel A: fused QKV projection.
//   q/k/v[e] = sum_c x[row][c] * W[e][c] + b[e], written in (B,H,S,D) layout.
//   Q and K pre-scaled by log2(e) so attention uses bare exp2 (v_exp_f32).
// grid = (256, 3), block = 128.
// ---------------------------------------------------------------------------
__global__ __launch_bounds__(128) void qkv_kernel(
    const float* __restrict__ x,
    const float* __restrict__ Wq, const float* __restrict__ bq,
    const float* __restrict__ Wk, const float* __restrict__ bk,
    const float* __restrict__ Wv, const float* __restrict__ bv,
    float* __restrict__ ws) {
  const int mat = blockIdx.y;
  const float* W    = (mat == 0) ? Wq : (mat == 1) ? Wk : Wv;
  const float* bias = (mat == 0) ? bq : (mat == 1) ? bk : bv;
  const float scale = (mat == 2) ? 1.0f : LOG2E;
  float* outbase = ws + (size_t)mat * BHSD;

  const int row0 = blockIdx.x * 8;
  const int t = threadIdx.x;

  __shared__ __align__(16) float xs[8 * E_];
  const float4* xg = (const float4*)(x + (size_t)row0 * E_);
  float4* xs4 = (float4*)xs;
  #pragma unroll
  for (int i = 0; i < 2; ++i) xs4[t + i * 128] = xg[t + i * 128];
  __syncthreads();

  const int col = t;
  const float4* W4 = (const float4*)(W + (size_t)col * E_);

  float acc[8];
  #pragma unroll
  for (int r = 0; r < 8; ++r) acc[r] = 0.f;

  #pragma unroll 4
  for (int c4 = 0; c4 < E_ / 4; ++c4) {
    float4 w = W4[c4];
    #pragma unroll
    for (int r = 0; r < 8; ++r) {
      float4 xv = xs4[r * (E_ / 4) + c4];
      acc[r] += xv.x * w.x + xv.y * w.y + xv.z * w.z + xv.w * w.w;
    }
  }

  const float bcol = bias[col];
  const int h = col >> 5, d = col & 31;
  #pragma unroll
  for (int r = 0; r < 8; ++r) {
    int row = row0 + r;
    int b = row >> 10, s = row & 1023;
    outbase[(((size_t)(b * H_ + h)) * S_ + s) * D_ + d] = (acc[r] + bcol) * scale;
  }
}

// ---------------------------------------------------------------------------
// Kernel B: ultrametric attention partials.
//   Lane = one Q row (q[32], o[32] in VGPRs). Block = 8 waves over the SAME
//   64 rows; wave w covers keys [kc*256 + w*32, +32) of this block's 256-key
//   chunk. K chunk staged in LDS once (coalesced); hot-loop K reads are
//   same-address -> HW broadcast. V read via global (no dep on dist -> slack).
//   dist >= 0 so p = exp2(-dist_scaled) needs no online rescaling in fp32.
// grid = 128 rt * 4 kc = 512 blocks, block = 512 (8 waves), <=128 VGPR.
// LDS union: K-stage [256][32] f32 (32 KB) during loop; merge buffers
// (sm_o[4][64][33] + sm_l[4][64], 34 KB) after a barrier.
// ---------------------------------------------------------------------------
#define SMEM_BYTES (4 * 64 * 33 * 4 + 4 * 64 * 4)   // 34816 > 32768

__global__ __launch_bounds__(512, 4) void attn_kernel(
    const float* __restrict__ qg, const float* __restrict__ kg,
    const float* __restrict__ vg,
    float* __restrict__ part_o, float* __restrict__ part_l) {
  __shared__ __align__(16) char smem[SMEM_BYTES];
  float* ks = (float*)smem;                                   // [256][32]
  float (*sm_o)[64][33] = (float (*)[64][33])smem;            // after loop
  float* sm_l = (float*)(smem + 4 * 64 * 33 * 4);

  const int rt = blockIdx.x >> 2;      // row tile 0..127
  const int kc = blockIdx.x & 3;       // key chunk 0..3
  const int t = threadIdx.x;
  const int w = t >> 6;                // wave 0..7
  const int lane = t & 63;
  const int bh = rt >> 4;              // head index (b*H + h)
  const int srow = (rt & 15) * 64 + lane;

  const float* kbase = kg + (size_t)bh * S_ * D_;
  const float* vbase = vg + (size_t)bh * S_ * D_;

  // ---- cooperative stage of this block's 256-key K chunk: 2048 float4 ----
  {
    const float4* kgt = (const float4*)(kbase + (size_t)kc * 256 * D_);
    float4* ks4 = (float4*)ks;
    #pragma unroll
    for (int i = 0; i < 4; ++i) {
      int f = t + i * 512;
      ks4[f] = kgt[f];
    }
  }

  // ---- Q row -> registers ----
  const float* qrow = qg + ((size_t)bh * S_ + srow) * D_;
  float q[32];
  #pragma unroll
  for (int i = 0; i < 8; ++i) {
    float4 v4 = *(const float4*)(qrow + i * 4);
    q[i * 4 + 0] = v4.x; q[i * 4 + 1] = v4.y;
    q[i * 4 + 2] = v4.z; q[i * 4 + 3] = v4.w;
  }

  float o[32];
  #pragma unroll
  for (int i = 0; i < 32; ++i) o[i] = 0.f;
  float l = 0.f;

  __syncthreads();   // K staged

  const int j0 = w * 32;                       // key offset within chunk
  const float* vchunk = vbase + ((size_t)kc * 256 + j0) * D_;

  #pragma unroll 2
  for (int jj = 0; jj < 32; ++jj) {
    const float* kr = ks + (size_t)(j0 + jj) * D_;   // same addr all lanes
    const float* vr = vchunk + (size_t)jj * D_;

    float kk[32];
    #pragma unroll
    for (int i = 0; i < 8; ++i) {
      float4 v4 = *(const float4*)(kr + i * 4);      // ds_read_b128 broadcast
      kk[i * 4 + 0] = v4.x; kk[i * 4 + 1] = v4.y;
      kk[i * 4 + 2] = v4.z; kk[i * 4 + 3] = v4.w;
    }

    // Chebyshev distance: 4 chains, max3-with-abs folding
    float c0 = 0.f, c1 = 0.f, c2 = 0.f, c3 = 0.f;
    #pragma unroll
    for (int i = 0; i < 4; ++i) {
      c0 = fmaxf(c0, fmaxf(fabsf(q[i*8+0] - kk[i*8+0]), fabsf(q[i*8+1] - kk[i*8+1])));
      c1 = fmaxf(c1, fmaxf(fabsf(q[i*8+2] - kk[i*8+2]), fabsf(q[i*8+3] - kk[i*8+3])));
      c2 = fmaxf(c2, fmaxf(fabsf(q[i*8+4] - kk[i*8+4]), fabsf(q[i*8+5] - kk[i*8+5])));
      c3 = fmaxf(c3, fmaxf(fabsf(q[i*8+6] - kk[i*8+6]), fabsf(q[i*8+7] - kk[i*8+7])));
    }
    const float dist = fmaxf(fmaxf(c0, c1), fmaxf(c2, c3));   // log2e-scaled
    const float p = exp2f(-dist);
    l += p;

    // O += p * V[j]  (uniform global loads; independent of dist -> slack)
    #pragma unroll
    for (int i = 0; i < 8; ++i) {
      float4 v4 = *(const float4*)(vr + i * 4);
      o[i * 4 + 0] = fmaf(p, v4.x, o[i * 4 + 0]);
      o[i * 4 + 1] = fmaf(p, v4.y, o[i * 4 + 1]);
      o[i * 4 + 2] = fmaf(p, v4.z, o[i * 4 + 2]);
      o[i * 4 + 3] = fmaf(p, v4.w, o[i * 4 + 3]);
    }
  }

  __syncthreads();   // all waves done reading ks -> safe to reuse LDS

  // ---- 8-wave merge (two phases), then write raw partial ----
  if (w >= 4) {
    #pragma unroll
    for (int e = 0; e < 32; ++e) sm_o[w - 4][lane][e] = o[e];
    sm_l[(w - 4) * 64 + lane] = l;
  }
  __syncthreads();
  if (w < 4) {
    #pragma unroll
    for (int e = 0; e < 32; ++e) sm_o[w][lane][e] += o[e];
    sm_l[w * 64 + lane] += l;
  }
  __syncthreads();

  const int row = t >> 3;             // 0..63
  const int sl = t & 7;               // dim slice: sl*4 .. sl*4+3
  float r4[4];
  #pragma unroll
  for (int e = 0; e < 4; ++e) {
    const int d = sl * 4 + e;
    r4[e] = sm_o[0][row][d] + sm_o[1][row][d] +
            sm_o[2][row][d] + sm_o[3][row][d];
  }
  float* po = part_o + ((size_t)(rt * 4 + kc) * 64 + row) * 32 + sl * 4;
  *(float4*)po = make_float4(r4[0], r4[1], r4[2], r4[3]);
  if (sl == 0) {
    part_l[(size_t)(rt * 4 + kc) * 64 + row] =
        sm_l[0 * 64 + row] + sm_l[1 * 64 + row] +
        sm_l[2 * 64 + row] + sm_l[3 * 64 + row];
  }
}

// ---------------------------------------------------------------------------
// Kernel C: merge kc-partials -> att rows in LDS -> out = att @ Wo^T + bo
// grid = 256 blocks (8 flat rows each), block = 128.
// ---------------------------------------------------------------------------
__global__ __launch_bounds__(128) void out_kernel(
    const float* __restrict__ part_o, const float* __restrict__ part_l,
    const float* __restrict__ Wo, const float* __restrict__ bo,
    float* __restrict__ out) {
  const int row0 = blockIdx.x * 8;
  const int t = threadIdx.x;

  __shared__ __align__(16) float xs[8 * E_];

  const int e = t;
  const int h = e >> 5, d = e & 31;
  #pragma unroll
  for (int i = 0; i < 8; ++i) {
    const int r = row0 + i;
    const int b = r >> 10, s = r & 1023;
    const int rt = (b * H_ + h) * 16 + (s >> 6);
    const int lrow = s & 63;
    float acc = 0.f, lsum = 0.f;
    #pragma unroll
    for (int kc = 0; kc < 4; ++kc) {
      const size_t base = (size_t)(rt * 4 + kc) * 64 + lrow;
      acc  += part_o[base * 32 + d];
      lsum += part_l[base];
    }
    xs[i * E_ + e] = acc / lsum;
  }
  __syncthreads();

  const int col = t;
  const float4* W4 = (const float4*)(Wo + (size_t)col * E_);
  const float4* xs4 = (const float4*)xs;

  float acc[8];
  #pragma unroll
  for (int r = 0; r < 8; ++r) acc[r] = 0.f;

  #pragma unroll 4
  for (int c4 = 0; c4 < E_ / 4; ++c4) {
    float4 w = W4[c4];
    #pragma unroll
    for (int r = 0; r < 8; ++r) {
      float4 xv = xs4[r * (E_ / 4) + c4];
      acc[r] += xv.x * w.x + xv.y * w.y + xv.z * w.z + xv.w * w.w;
    }
  }

  const float bcol = bo[col];
  #pragma unroll
  for (int r = 0; r < 8; ++r)
    out[(size_t)(row0 + r) * E_ + col] = acc[r] + bcol;
}

// ---------------------------------------------------------------------------
extern "C" void kernel_launch(void* const* d_in, const int* in_sizes, int n_in,
                              void* d_out, int out_size, void* d_ws, size_t ws_size,
                              hipStream_t stream) {
  const float* x  = (const float*)d_in[0];
  const float* Wq = (const float*)d_in[1];
  const float* bq = (const float*)d_in[2];
  const float* Wk = (const float*)d_in[3];
  const float* bk = (const float*)d_in[4];
  const float* Wv = (const float*)d_in[5];
  const float* bv = (const float*)d_in[6];
  const float* Wo = (const float*)d_in[7];
  const float* bo = (const float*)d_in[8];
  float* ws  = (float*)d_ws;
  float* out = (float*)d_out;

  // ws layout (floats):
  //   [0, BHSD)          q (log2e-scaled)
  //   [BHSD, 2*BHSD)     k (log2e-scaled)
  //   [2*BHSD, 3*BHSD)   v
  //   [3*BHSD, +1048576) part_o : [128 rt][4 kc][64 row][32 d]
  //   then 32768         part_l : [128 rt][4 kc][64 row]
  float* qd = ws;
  float* kd = ws + (size_t)BHSD;
  float* vd = ws + 2 * (size_t)BHSD;
  float* part_o = ws + 3 * (size_t)BHSD;
  float* part_l = part_o + (size_t)128 * 4 * 64 * 32;

  qkv_kernel<<<dim3((B_ * S_) / 8, 3), 128, 0, stream>>>(x, Wq, bq, Wk, bk, Wv, bv, ws);
  attn_kernel<<<dim3(128 * 4), 512, 0, stream>>>(qd, kd, vd, part_o, part_l);
  out_kernel<<<dim3((B_ * S_) / 8), 128, 0, stream>>>(part_o, part_l, Wo, bo, out);
}

// Round 6
// 63.002 us; speedup vs baseline: 1.6462x; 1.1852x over previous
//
#include <hip/hip_runtime.h>
#include <hip/hip_bf16.h>

#define B_ 2
#define S_ 1024
#define E_ 128
#define H_ 4
#define D_ 32
#define BHSD (B_ * H_ * S_ * D_)   // 262144 floats per tensor
#define LOG2E 1.44269504088896f

// ---------------------------------------------------------------------------
// Kernel A: fused QKV projection.
//   q/k/v[e] = sum_c x[row][c] * W[e][c] + b[e], written in (B,H,S,D) layout.
//   Q and K pre-scaled by log2(e) so attention uses bare exp2 (v_exp_f32).
// grid = (256, 3), block = 128.
// ---------------------------------------------------------------------------
__global__ __launch_bounds__(128) void qkv_kernel(
    const float* __restrict__ x,
    const float* __restrict__ Wq, const float* __restrict__ bq,
    const float* __restrict__ Wk, const float* __restrict__ bk,
    const float* __restrict__ Wv, const float* __restrict__ bv,
    float* __restrict__ ws) {
  const int mat = blockIdx.y;
  const float* W    = (mat == 0) ? Wq : (mat == 1) ? Wk : Wv;
  const float* bias = (mat == 0) ? bq : (mat == 1) ? bk : bv;
  const float scale = (mat == 2) ? 1.0f : LOG2E;
  float* outbase = ws + (size_t)mat * BHSD;

  const int row0 = blockIdx.x * 8;
  const int t = threadIdx.x;

  __shared__ __align__(16) float xs[8 * E_];
  const float4* xg = (const float4*)(x + (size_t)row0 * E_);
  float4* xs4 = (float4*)xs;
  #pragma unroll
  for (int i = 0; i < 2; ++i) xs4[t + i * 128] = xg[t + i * 128];
  __syncthreads();

  const int col = t;
  const float4* W4 = (const float4*)(W + (size_t)col * E_);

  float acc[8];
  #pragma unroll
  for (int r = 0; r < 8; ++r) acc[r] = 0.f;

  #pragma unroll 4
  for (int c4 = 0; c4 < E_ / 4; ++c4) {
    float4 w = W4[c4];
    #pragma unroll
    for (int r = 0; r < 8; ++r) {
      float4 xv = xs4[r * (E_ / 4) + c4];
      acc[r] += xv.x * w.x + xv.y * w.y + xv.z * w.z + xv.w * w.w;
    }
  }

  const float bcol = bias[col];
  const int h = col >> 5, d = col & 31;
  #pragma unroll
  for (int r = 0; r < 8; ++r) {
    int row = row0 + r;
    int b = row >> 10, s = row & 1023;
    outbase[(((size_t)(b * H_ + h)) * S_ + s) * D_ + d] = (acc[r] + bcol) * scale;
  }
}

// ---------------------------------------------------------------------------
// Kernel B: ultrametric attention partials, d-split lane layout.
//   Lane (h = lane>>5, r = lane&31) owns HALF a Q row: q[16], o[16] in VGPRs.
//   Wave = 32 rows x 2 halves. dist = max over own half, combined with the
//   partner lane via __shfl_xor(.,32). K chunk staged in LDS (reads are
//   2-distinct-address per wave -> broadcast). V read from global (L2/L1
//   resident). Explicit 1-deep prefetch pipeline for K and V (one-past-end
//   prefetch lands in adjacent ws regions: valid memory, discarded).
//   dist >= 0 so p = exp2(-dist_scaled) needs no online rescaling in fp32.
// grid = 256 row-tiles * 4 kc = 1024 blocks, block = 512 (8 waves).
// Wave w covers keys [kc*256 + w*32, +32).
// waves_per_eu(4,4): pins 128-VGPR budget (no AGPR churn, prefetch headroom).
// LDS union: K-stage [256][32] f32 (32 KB) during loop; merge buffers
// sm_o[8][32][36] + sm_l[8][32] (37.9 KB) after a barrier.
// ---------------------------------------------------------------------------
#define SMEM_BYTES (8 * 32 * 36 * 4 + 8 * 32 * 4)   // 37888 > 32768

__global__ __launch_bounds__(512)
__attribute__((amdgpu_waves_per_eu(4, 4)))
void attn_kernel(
    const float* __restrict__ qg, const float* __restrict__ kg,
    const float* __restrict__ vg,
    float* __restrict__ part_o, float* __restrict__ part_l) {
  __shared__ __align__(16) char smem[SMEM_BYTES];
  float* ks = (float*)smem;                               // [256][32]
  float (*sm_o)[32][36] = (float (*)[32][36])smem;        // after loop
  float* sm_l = (float*)(smem + 8 * 32 * 36 * 4);         // [8][32]

  const int rt = blockIdx.x >> 2;      // row tile 0..255 (32 rows each)
  const int kc = blockIdx.x & 3;       // key chunk 0..3
  const int t = threadIdx.x;
  const int w = t >> 6;                // wave 0..7
  const int lane = t & 63;
  const int h = lane >> 5;             // d-half 0..1
  const int r = lane & 31;             // row within tile
  const int bh = rt >> 5;              // head index (b*H + h) 0..7
  const int srow = (rt & 31) * 32 + r;

  const float* kbase = kg + (size_t)bh * S_ * D_;
  const float* vbase = vg + (size_t)bh * S_ * D_;

  // ---- cooperative stage of this block's 256-key K chunk: 2048 float4 ----
  {
    const float4* kgt = (const float4*)(kbase + (size_t)kc * 256 * D_);
    float4* ks4 = (float4*)ks;
    #pragma unroll
    for (int i = 0; i < 4; ++i) {
      int f = t + i * 512;
      ks4[f] = kgt[f];
    }
  }

  // ---- my Q half-row -> registers (independent of staging) ----
  const float* qrow = qg + ((size_t)bh * S_ + srow) * D_ + h * 16;
  float4 q0 = *(const float4*)(qrow + 0);
  float4 q1 = *(const float4*)(qrow + 4);
  float4 q2 = *(const float4*)(qrow + 8);
  float4 q3 = *(const float4*)(qrow + 12);

  float o[16];
  #pragma unroll
  for (int i = 0; i < 16; ++i) o[i] = 0.f;
  float l = 0.f;

  __syncthreads();   // K staged

  const float* kLds = ks + (size_t)(w * 32) * D_ + h * 16;
  const float* vGlb = vbase + ((size_t)(kc * 256) + w * 32) * D_ + h * 16;

  // prologue: load key 0
  float4 ka0 = *(const float4*)(kLds + 0);
  float4 ka1 = *(const float4*)(kLds + 4);
  float4 ka2 = *(const float4*)(kLds + 8);
  float4 ka3 = *(const float4*)(kLds + 12);
  float4 va0 = *(const float4*)(vGlb + 0);
  float4 va1 = *(const float4*)(vGlb + 4);
  float4 va2 = *(const float4*)(vGlb + 8);
  float4 va3 = *(const float4*)(vGlb + 12);

  #pragma unroll 4
  for (int jj = 0; jj < 32; ++jj) {
    // prefetch key jj+1 (one-past-end is valid ws memory, discarded)
    const float* kn = kLds + (size_t)(jj + 1) * D_;
    const float* vn = vGlb + (size_t)(jj + 1) * D_;
    float4 kb0 = *(const float4*)(kn + 0);
    float4 kb1 = *(const float4*)(kn + 4);
    float4 kb2 = *(const float4*)(kn + 8);
    float4 kb3 = *(const float4*)(kn + 12);
    float4 vb0 = *(const float4*)(vn + 0);
    float4 vb1 = *(const float4*)(vn + 4);
    float4 vb2 = *(const float4*)(vn + 8);
    float4 vb3 = *(const float4*)(vn + 12);

    // Chebyshev half-distance: 16 sub + 8 max3(abs,abs,chain)
    float c0 = 0.f, c1 = 0.f;
    c0 = fmaxf(c0, fmaxf(fabsf(q0.x - ka0.x), fabsf(q0.y - ka0.y)));
    c1 = fmaxf(c1, fmaxf(fabsf(q0.z - ka0.z), fabsf(q0.w - ka0.w)));
    c0 = fmaxf(c0, fmaxf(fabsf(q1.x - ka1.x), fabsf(q1.y - ka1.y)));
    c1 = fmaxf(c1, fmaxf(fabsf(q1.z - ka1.z), fabsf(q1.w - ka1.w)));
    c0 = fmaxf(c0, fmaxf(fabsf(q2.x - ka2.x), fabsf(q2.y - ka2.y)));
    c1 = fmaxf(c1, fmaxf(fabsf(q2.z - ka2.z), fabsf(q2.w - ka2.w)));
    c0 = fmaxf(c0, fmaxf(fabsf(q3.x - ka3.x), fabsf(q3.y - ka3.y)));
    c1 = fmaxf(c1, fmaxf(fabsf(q3.z - ka3.z), fabsf(q3.w - ka3.w)));
    float dh = fmaxf(c0, c1);
    // combine with partner half
    float dist = fmaxf(dh, __shfl_xor(dh, 32));
    float p = exp2f(-dist);          // dist pre-scaled by log2e
    l += p;

    o[ 0] = fmaf(p, va0.x, o[ 0]); o[ 1] = fmaf(p, va0.y, o[ 1]);
    o[ 2] = fmaf(p, va0.z, o[ 2]); o[ 3] = fmaf(p, va0.w, o[ 3]);
    o[ 4] = fmaf(p, va1.x, o[ 4]); o[ 5] = fmaf(p, va1.y, o[ 5]);
    o[ 6] = fmaf(p, va1.z, o[ 6]); o[ 7] = fmaf(p, va1.w, o[ 7]);
    o[ 8] = fmaf(p, va2.x, o[ 8]); o[ 9] = fmaf(p, va2.y, o[ 9]);
    o[10] = fmaf(p, va2.z, o[10]); o[11] = fmaf(p, va2.w, o[11]);
    o[12] = fmaf(p, va3.x, o[12]); o[13] = fmaf(p, va3.y, o[13]);
    o[14] = fmaf(p, va3.z, o[14]); o[15] = fmaf(p, va3.w, o[15]);

    ka0 = kb0; ka1 = kb1; ka2 = kb2; ka3 = kb3;
    va0 = vb0; va1 = vb1; va2 = vb2; va3 = vb3;
  }

  __syncthreads();   // all waves done reading ks -> safe to reuse LDS

  // ---- write per-wave half-partials, merge 8 waves, write raw partial ----
  {
    float* dst = &sm_o[w][r][h * 16];
    #pragma unroll
    for (int e = 0; e < 4; ++e)
      *(float4*)(dst + e * 4) = make_float4(o[e*4+0], o[e*4+1], o[e*4+2], o[e*4+3]);
    if (h == 0) sm_l[w * 32 + r] = l;
  }
  __syncthreads();

  #pragma unroll
  for (int pi = 0; pi < 2; ++pi) {
    const int id = t + pi * 512;       // 0..1023 = 32 rows x 32 dims
    const int rr = id >> 5, dd = id & 31;
    float s = 0.f;
    #pragma unroll
    for (int ww = 0; ww < 8; ++ww) s += sm_o[ww][rr][dd];
    part_o[((size_t)(rt * 4 + kc) * 32 + rr) * 32 + dd] = s;
  }
  if (t < 32) {
    float s = 0.f;
    #pragma unroll
    for (int ww = 0; ww < 8; ++ww) s += sm_l[ww * 32 + t];
    part_l[(size_t)(rt * 4 + kc) * 32 + t] = s;
  }
}

// ---------------------------------------------------------------------------
// Kernel C: merge kc-partials -> att rows in LDS -> out = att @ Wo^T + bo
// grid = 256 blocks (8 flat rows each), block = 128.
// ---------------------------------------------------------------------------
__global__ __launch_bounds__(128) void out_kernel(
    const float* __restrict__ part_o, const float* __restrict__ part_l,
    const float* __restrict__ Wo, const float* __restrict__ bo,
    float* __restrict__ out) {
  const int row0 = blockIdx.x * 8;
  const int t = threadIdx.x;

  __shared__ __align__(16) float xs[8 * E_];

  const int e = t;
  const int h = e >> 5, d = e & 31;
  #pragma unroll
  for (int i = 0; i < 8; ++i) {
    const int r = row0 + i;
    const int b = r >> 10, s = r & 1023;
    const int rt = (b * H_ + h) * 32 + (s >> 5);   // 32-row tiles now
    const int lrow = s & 31;
    float acc = 0.f, lsum = 0.f;
    #pragma unroll
    for (int kc = 0; kc < 4; ++kc) {
      const size_t base = (size_t)(rt * 4 + kc) * 32 + lrow;
      acc  += part_o[base * 32 + d];
      lsum += part_l[base];
    }
    xs[i * E_ + e] = acc / lsum;
  }
  __syncthreads();

  const int col = t;
  const float4* W4 = (const float4*)(Wo + (size_t)col * E_);
  const float4* xs4 = (const float4*)xs;

  float acc[8];
  #pragma unroll
  for (int r = 0; r < 8; ++r) acc[r] = 0.f;

  #pragma unroll 4
  for (int c4 = 0; c4 < E_ / 4; ++c4) {
    float4 w = W4[c4];
    #pragma unroll
    for (int r = 0; r < 8; ++r) {
      float4 xv = xs4[r * (E_ / 4) + c4];
      acc[r] += xv.x * w.x + xv.y * w.y + xv.z * w.z + xv.w * w.w;
    }
  }

  const float bcol = bo[col];
  #pragma unroll
  for (int r = 0; r < 8; ++r)
    out[(size_t)(row0 + r) * E_ + col] = acc[r] + bcol;
}

// ---------------------------------------------------------------------------
extern "C" void kernel_launch(void* const* d_in, const int* in_sizes, int n_in,
                              void* d_out, int out_size, void* d_ws, size_t ws_size,
                              hipStream_t stream) {
  const float* x  = (const float*)d_in[0];
  const float* Wq = (const float*)d_in[1];
  const float* bq = (const float*)d_in[2];
  const float* Wk = (const float*)d_in[3];
  const float* bk = (const float*)d_in[4];
  const float* Wv = (const float*)d_in[5];
  const float* bv = (const float*)d_in[6];
  const float* Wo = (const float*)d_in[7];
  const float* bo = (const float*)d_in[8];
  float* ws  = (float*)d_ws;
  float* out = (float*)d_out;

  // ws layout (floats):
  //   [0, BHSD)          q (log2e-scaled)
  //   [BHSD, 2*BHSD)     k (log2e-scaled)
  //   [2*BHSD, 3*BHSD)   v
  //   [3*BHSD, +1048576) part_o : [256 rt][4 kc][32 row][32 d]
  //   then 32768         part_l : [256 rt][4 kc][32 row]
  float* qd = ws;
  float* kd = ws + (size_t)BHSD;
  float* vd = ws + 2 * (size_t)BHSD;
  float* part_o = ws + 3 * (size_t)BHSD;
  float* part_l = part_o + (size_t)256 * 4 * 32 * 32;

  qkv_kernel<<<dim3((B_ * S_) / 8, 3), 128, 0, stream>>>(x, Wq, bq, Wk, bk, Wv, bv, ws);
  attn_kernel<<<dim3(256 * 4), 512, 0, stream>>>(qd, kd, vd, part_o, part_l);
  out_kernel<<<dim3((B_ * S_) / 8), 128, 0, stream>>>(part_o, part_l, Wo, bo, out);
}